// Round 6
// baseline (110.325 us; speedup 1.0000x reference)
//
#include <hip/hip_runtime.h>
#include <math.h>

typedef short short8 __attribute__((ext_vector_type(8)));
typedef float f32x4 __attribute__((ext_vector_type(4)));

#define B_N 2048
#define NKM 9
#define CP 512          // C*4, K-order pc = p*128 + c
#define KU 128          // MUL
#define INV_SQRT_MUL 0.08838834764831845f   // 1/sqrt(128)
#define INV_SQRT_4C  0.04419417382415922f   // 1/sqrt(512)

// persistent device scratch; fully rewritten every launch before any read
__device__ ushort g_xb1[NKM * B_N * KU];          // [km][b][u] bf16
__device__ ushort g_xb2[NKM * B_N * KU];
__device__ ushort g_W1bt[3 * CP * KU];            // [l][pc][u] bf16, * 1/sqrt(128)
__device__ ushort g_W2bt[3 * CP * KU];
__device__ ushort g_Woutbt[3 * KU * CP];          // [l][u][pc] bf16, * 1/sqrt(512)
__device__ ushort g_c1b[(size_t)B_N * NKM * CP];  // [b][km][pc] bf16
__device__ ushort g_c2b[(size_t)B_N * NKM * CP];
__device__ ushort g_cb[(size_t)B_N * NKM * CP];   // c_out, [b][km][pc] bf16

__device__ __forceinline__ ushort f2b(float f) {
    uint u = __float_as_uint(f);
    uint r = (u + 0x7fffu + ((u >> 16) & 1u)) >> 16;   // RNE
    return (ushort)r;
}
__device__ __forceinline__ float b2f(ushort h) {
    return __uint_as_float(((uint)h) << 16);
}
__device__ __forceinline__ int l_of_km(int km) { return (km >= 4) ? 2 : (km >= 1 ? 1 : 0); }

// ---------------------------------------------------------------------------
// Gaunt tensor for real orthonormal SH, l<=2: 83 nonzeros, 7 distinct values,
// derived in closed form (sphere moments). Invariant to the Condon-Shortley
// sign convention (every nonzero has an even # of sign-flipped indices).
// ---------------------------------------------------------------------------
__host__ __device__ constexpr int lof(int n) { return n >= 4 ? 2 : (n >= 1 ? 1 : 0); }
__host__ __device__ constexpr int mof(int n) { int l = lof(n); return n - l * l - l; }
__host__ __device__ constexpr bool gaunt_nz(int a, int b, int c) {
    int la = lof(a), lb = lof(b), lc = lof(c);
    if ((la + lb + lc) & 1) return false;
    if (lc > la + lb || la > lb + lc || lb > lc + la) return false;
    int ma = mof(a), mb = mof(b), mc = mof(c);
    int neg = (ma < 0) + (mb < 0) + (mc < 0);
    if (neg & 1) return false;
    int A = ma < 0 ? -ma : ma, Bm = mb < 0 ? -mb : mb, Cm = mc < 0 ? -mc : mc;
    return (A + Bm == Cm) || (Bm + Cm == A) || (Cm + A == Bm);
}
__host__ __device__ constexpr float gaunt_val(int a, int b, int c) {
    // sort the triple (G is fully symmetric)
    int x = a, y = b, z = c, t = 0;
    if (x > y) { t = x; x = y; y = t; }
    if (y > z) { t = y; y = z; z = t; }
    if (x > y) { t = x; x = y; y = t; }
    const float C00 = 0.28209479177387814f;   // 1/(2*sqrt(pi))
    const float A_  = 0.12615662610100802f;
    const float B_  = 0.25231325220201604f;
    const float C_  = 0.21850968611841584f;
    const float D_  = 0.18022375157286857f;
    const float E_  = 0.09011187578643429f;
    const float F_  = 0.15607834722743988f;
    if (x == 0) return C00;                       // (0,k,k)
    if (y <= 3) {                                 // {l1,l1,l2}
        if (z == 6) return (y == 2) ? B_ : -A_;   // (1,1,6),(3,3,6)->-A ; (2,2,6)->B
        if (z == 8) return (x == 1) ? -C_ : C_;   // (1,1,8)->-C ; (3,3,8)->C
        return C_;                                // (1,3,4),(1,2,5),(2,3,7)
    }
    if (x == 4) return (y == 4) ? -D_ : F_;       // (4,4,6)->-D ; (4,5,7)->F
    if (x == 5) return (z == 6) ? E_ : -F_;       // (5,5,6)->E ; (5,5,8)->-F
    if (x == 6) return (y == 6) ? D_ : ((y == 7) ? E_ : -D_); // (6,6,6),(6,7,7),(6,8,8)
    return F_;                                    // (7,7,8)
}

// ---------------------------------------------------------------------------
// prep_small: W1/W2 -> [l][pc][u]*inv_sqrt(128); Wout -> [l][u][pc]*inv_sqrt(512)
// ---------------------------------------------------------------------------
__global__ void prep_small_kernel(const float* __restrict__ W1, const float* __restrict__ W2,
                                  const float* __restrict__ Wout) {
    int idx = blockIdx.x * 256 + threadIdx.x;    // < 3*512*128 = 196608
    int l = idx >> 16;
    int r = idx & 65535;
    {   // W1bt/W2bt [l][pc][u] <- W[l][u][c*4+p]
        int pc = r >> 7, u = r & 127;
        int cc = pc & 127, pp = pc >> 7;
        size_t src = (size_t)l * 65536 + (size_t)u * 512 + cc * 4 + pp;
        g_W1bt[idx] = f2b(W1[src] * INV_SQRT_MUL);
        g_W2bt[idx] = f2b(W2[src] * INV_SQRT_MUL);
    }
    {   // Woutbt [l][u][pc] <- Wout[l][c*4+p][u]
        int u = r >> 9, pc = r & 511;
        int cc = pc & 127, pp = pc >> 7;
        g_Woutbt[idx] = f2b(Wout[(size_t)l * 65536 + (size_t)(cc * 4 + pp) * 128 + u] * INV_SQRT_4C);
    }
}

// ---------------------------------------------------------------------------
// prep_x: x [B,2048] fp32 -> xb [km][B][u] bf16 via LDS transpose
// ---------------------------------------------------------------------------
__global__ __launch_bounds__(256) void prep_x_kernel(const float* __restrict__ x1,
                                                     const float* __restrict__ x2) {
    __shared__ float L1[2048], L2[2048];
    int b = blockIdx.x, tid = threadIdx.x;
    const float4* r1 = (const float4*)(x1 + (size_t)b * 2048);
    const float4* r2 = (const float4*)(x2 + (size_t)b * 2048);
    #pragma unroll
    for (int i = 0; i < 2; ++i) {
        int q = i * 256 + tid;
        *(float4*)&L1[q * 4] = r1[q];
        *(float4*)&L2[q * 4] = r2[q];
    }
    __syncthreads();
    #pragma unroll
    for (int i = 0; i < 9; ++i) {
        int e = i * 256 + tid;                    // < 2304 = 2 fields * 9 km * 128 u
        int field = e >= 1152;
        int r = e - field * 1152;
        int km = r >> 7, u = r & 127;
        int l = l_of_km(km);
        int col = l * l * 128 + u * (2 * l + 1) + (km - l * l);
        float v = field ? L2[col] : L1[col];
        ushort* dst = field ? g_xb2 : g_xb1;
        dst[(size_t)km * (B_N * KU) + (size_t)b * KU + u] = f2b(v);
    }
}

// ---------------------------------------------------------------------------
// zero_tail: out columns [1152, 2048) = l=3 zero block
// ---------------------------------------------------------------------------
__global__ void zero_tail_kernel(float* __restrict__ out) {
    int idx = blockIdx.x * 256 + threadIdx.x;   // < 2048*224
    int b = idx / 224, q = idx - b * 224;
    *(float4*)&out[(size_t)b * 2048 + 1152 + q * 4] = make_float4(0.f, 0.f, 0.f, 0.f);
}

// ---------------------------------------------------------------------------
// gemm_c: c[b][km][pc] = sum_u xb[km][b][u] * Wbt[l][pc][u]   (bf16 out)
// grid (32, 8, 18 = field*9+km), 64x64 tile, K=128 resident, XOR-swizzled LDS
// ---------------------------------------------------------------------------
__global__ __launch_bounds__(256) void gemm_c_kernel() {
    __shared__ ushort As[64 * 128];
    __shared__ ushort Bs[64 * 128];
    int tid = threadIdx.x;
    int z = blockIdx.z;
    int field = (z >= NKM);
    int km = field ? z - NKM : z;
    int l = l_of_km(km);
    int b0 = blockIdx.x * 64, n0 = blockIdx.y * 64;
    const ushort* xa = (field ? g_xb2 : g_xb1) + (size_t)km * (B_N * KU);
    const ushort* wb = (field ? g_W2bt : g_W1bt) + (size_t)l * 65536;
    ushort* cdst = field ? g_c2b : g_c1b;

    #pragma unroll
    for (int it = 0; it < 4; ++it) {
        int i = it * 256 + tid;            // 16B chunk id, 0..1023
        int row = i >> 4, kg = i & 15;
        int dst = row * 128 + ((kg ^ (row & 7)) << 3);
        *(short8*)&As[dst] = *(const short8*)&xa[(size_t)(b0 + row) * KU + (kg << 3)];
        *(short8*)&Bs[dst] = *(const short8*)&wb[(size_t)(n0 + row) * KU + (kg << 3)];
    }
    __syncthreads();

    int lane = tid & 63, wid = tid >> 6, wr = wid >> 1, wc = wid & 1;
    f32x4 acc[2][2];
    #pragma unroll
    for (int i = 0; i < 2; ++i)
        #pragma unroll
        for (int j = 0; j < 2; ++j) acc[i][j] = (f32x4){0.f, 0.f, 0.f, 0.f};

    #pragma unroll
    for (int ks = 0; ks < 4; ++ks) {
        int kg = ks * 4 + (lane >> 4);
        short8 a[2], b[2];
        #pragma unroll
        for (int i = 0; i < 2; ++i) {
            int row = wr * 32 + i * 16 + (lane & 15);
            a[i] = *(const short8*)&As[row * 128 + ((kg ^ (row & 7)) << 3)];
        }
        #pragma unroll
        for (int j = 0; j < 2; ++j) {
            int row = wc * 32 + j * 16 + (lane & 15);
            b[j] = *(const short8*)&Bs[row * 128 + ((kg ^ (row & 7)) << 3)];
        }
        #pragma unroll
        for (int i = 0; i < 2; ++i)
            #pragma unroll
            for (int j = 0; j < 2; ++j)
                acc[i][j] = __builtin_amdgcn_mfma_f32_16x16x32_bf16(a[i], b[j], acc[i][j], 0, 0, 0);
    }

    #pragma unroll
    for (int i = 0; i < 2; ++i)
        #pragma unroll
        for (int j = 0; j < 2; ++j)
            #pragma unroll
            for (int r = 0; r < 4; ++r) {
                int row = b0 + wr * 32 + i * 16 + ((lane >> 4) << 2) + r;
                int col = n0 + wc * 32 + j * 16 + (lane & 15);
                cdst[((size_t)row * NKM + km) * CP + col] = f2b(acc[i][j][r]);
            }
}

// ---------------------------------------------------------------------------
// middle v3: one block (512 thr) per b-row. Stage c1/c2 rows (2x9KB) in LDS
// with coalesced ushort4 loads; thread (p = tid>>7, c = tid&127) does the
// constexpr-Gaunt contraction from LDS (2B/lane consecutive -> conflict-free).
// ---------------------------------------------------------------------------
__global__ __launch_bounds__(512) void middle_kernel() {
    __shared__ ushort c1s[NKM * CP];   // 9216 B
    __shared__ ushort c2s[NKM * CP];
    int tid = threadIdx.x;
    int b = blockIdx.x;
    const ushort* src1 = g_c1b + (size_t)b * (NKM * CP);
    const ushort* src2 = g_c2b + (size_t)b * (NKM * CP);

    // stage: 1152 ushort4-chunks per field
    #pragma unroll
    for (int i = 0; i < 2; ++i) {
        int ch = i * 512 + tid;
        *(ushort4*)&c1s[ch * 4] = *(const ushort4*)&src1[ch * 4];
        *(ushort4*)&c2s[ch * 4] = *(const ushort4*)&src2[ch * 4];
    }
    if (tid < 128) {
        int ch = 1024 + tid;
        *(ushort4*)&c1s[ch * 4] = *(const ushort4*)&src1[ch * 4];
        *(ushort4*)&c2s[ch * 4] = *(const ushort4*)&src2[ch * 4];
    }
    __syncthreads();

    int p = tid >> 7;          // wave-uniform
    int c = tid & 127;

    float o[9];
    #pragma unroll
    for (int k = 0; k < 9; ++k) o[k] = 0.f;

    if (p == 0) {
        float A1[9], A2[9];
        #pragma unroll
        for (int k = 0; k < 9; ++k) {
            A1[k] = b2f(c1s[k * CP + c]);
            A2[k] = b2f(c2s[k * CP + c]);
        }
        #pragma unroll
        for (int kk = 0; kk < 9; ++kk)
            #pragma unroll
            for (int i = 0; i < 9; ++i)
                #pragma unroll
                for (int j = 0; j < 9; ++j)
                    if (gaunt_nz(kk, i, j))
                        o[kk] = fmaf(gaunt_val(kk, i, j), A1[i] * A2[j], o[kk]);
    } else {
        int qa = (p == 1) ? 2 : (p == 2) ? 3 : 1;
        int qb = (p == 1) ? 3 : (p == 2) ? 1 : 2;
        float A1[9], B1[9], A2[9], B2[9];
        #pragma unroll
        for (int k = 0; k < 9; ++k) {
            A1[k] = b2f(c1s[k * CP + qa * 128 + c]);
            B1[k] = b2f(c1s[k * CP + qb * 128 + c]);
            A2[k] = b2f(c2s[k * CP + qa * 128 + c]);
            B2[k] = b2f(c2s[k * CP + qb * 128 + c]);
        }
        #pragma unroll
        for (int kk = 0; kk < 9; ++kk)
            #pragma unroll
            for (int i = 0; i < 9; ++i)
                #pragma unroll
                for (int j = 0; j < 9; ++j)
                    if (gaunt_nz(kk, i, j))
                        o[kk] = fmaf(gaunt_val(kk, i, j),
                                     fmaf(A1[i], B2[j], -(B1[i] * A2[j])), o[kk]);
    }

    ushort* w = g_cb + (size_t)b * (NKM * CP) + p * 128 + c;
    #pragma unroll
    for (int k = 0; k < 9; ++k) w[k * CP] = f2b(o[k]);
}

// ---------------------------------------------------------------------------
// out_gemm: out[b][OFF_l + u*d + mi] = sum_pc c_out[b][km][pc] * Woutbt[l][u][pc]
// grid (32, 2, 9 km), 64x64 tile, K=512 in 4 chunks
// ---------------------------------------------------------------------------
__global__ __launch_bounds__(256) void out_gemm_kernel(float* __restrict__ out) {
    __shared__ ushort As[64 * 128];
    __shared__ ushort Bs[64 * 128];
    int tid = threadIdx.x;
    int km = blockIdx.z;
    int l = l_of_km(km);
    int mi = km - l * l, d = 2 * l + 1, OFF = 128 * l * l;
    int b0 = blockIdx.x * 64, u0 = blockIdx.y * 64;

    int lane = tid & 63, wid = tid >> 6, wr = wid >> 1, wc = wid & 1;
    f32x4 acc[2][2];
    #pragma unroll
    for (int i = 0; i < 2; ++i)
        #pragma unroll
        for (int j = 0; j < 2; ++j) acc[i][j] = (f32x4){0.f, 0.f, 0.f, 0.f};

    for (int kc = 0; kc < 4; ++kc) {
        #pragma unroll
        for (int it = 0; it < 4; ++it) {
            int i = it * 256 + tid;
            int row = i >> 4, kg = i & 15;
            int dst = row * 128 + ((kg ^ (row & 7)) << 3);
            *(short8*)&As[dst] = *(const short8*)&g_cb[(size_t)(b0 + row) * (NKM * CP)
                                                       + (size_t)km * CP + kc * 128 + (kg << 3)];
            *(short8*)&Bs[dst] = *(const short8*)&g_Woutbt[(size_t)l * 65536
                                                       + (size_t)(u0 + row) * CP + kc * 128 + (kg << 3)];
        }
        __syncthreads();
        #pragma unroll
        for (int ks = 0; ks < 4; ++ks) {
            int kg = ks * 4 + (lane >> 4);
            short8 a[2], b[2];
            #pragma unroll
            for (int i = 0; i < 2; ++i) {
                int row = wr * 32 + i * 16 + (lane & 15);
                a[i] = *(const short8*)&As[row * 128 + ((kg ^ (row & 7)) << 3)];
            }
            #pragma unroll
            for (int j = 0; j < 2; ++j) {
                int row = wc * 32 + j * 16 + (lane & 15);
                b[j] = *(const short8*)&Bs[row * 128 + ((kg ^ (row & 7)) << 3)];
            }
            #pragma unroll
            for (int i = 0; i < 2; ++i)
                #pragma unroll
                for (int j = 0; j < 2; ++j)
                    acc[i][j] = __builtin_amdgcn_mfma_f32_16x16x32_bf16(a[i], b[j], acc[i][j], 0, 0, 0);
        }
        __syncthreads();
    }

    #pragma unroll
    for (int i = 0; i < 2; ++i)
        #pragma unroll
        for (int j = 0; j < 2; ++j)
            #pragma unroll
            for (int r = 0; r < 4; ++r) {
                int row = b0 + wr * 32 + i * 16 + ((lane >> 4) << 2) + r;
                int u   = u0 + wc * 32 + j * 16 + (lane & 15);
                out[(size_t)row * 2048 + OFF + u * d + mi] = acc[i][j][r];
            }
}

// ---------------------------------------------------------------------------
extern "C" void kernel_launch(void* const* d_in, const int* in_sizes, int n_in,
                              void* d_out, int out_size, void* d_ws, size_t ws_size,
                              hipStream_t stream) {
    const float* x1   = (const float*)d_in[0];
    const float* x2   = (const float*)d_in[1];
    const float* W1   = (const float*)d_in[2];
    const float* W2   = (const float*)d_in[3];
    const float* Wout = (const float*)d_in[4];
    float* out = (float*)d_out;

    zero_tail_kernel<<<1792, 256, 0, stream>>>(out);
    prep_small_kernel<<<768, 256, 0, stream>>>(W1, W2, Wout);
    prep_x_kernel<<<B_N, 256, 0, stream>>>(x1, x2);

    gemm_c_kernel<<<dim3(B_N / 64, CP / 64, 18), 256, 0, stream>>>();
    middle_kernel<<<B_N, 512, 0, stream>>>();
    out_gemm_kernel<<<dim3(B_N / 64, 128 / 64, NKM), 256, 0, stream>>>(out);
}

// Round 7
// 81.451 us; speedup vs baseline: 1.3545x; 1.3545x over previous
//
#include <hip/hip_runtime.h>
#include <math.h>

typedef short short8 __attribute__((ext_vector_type(8)));
typedef float f32x4 __attribute__((ext_vector_type(4)));

#define B_N 2048
#define NKM 9
#define CP 512          // C*4, K-order cp = c*4 + p  (p fastest)
#define KU 128          // MUL
#define INV_SQRT_MUL 0.08838834764831845f   // 1/sqrt(128)
#define INV_SQRT_4C  0.04419417382415922f   // 1/sqrt(512)

// persistent device scratch; fully rewritten every launch before any read
__device__ ushort g_xb1[NKM * B_N * KU];          // [km][b][u] bf16
__device__ ushort g_xb2[NKM * B_N * KU];
__device__ ushort g_W1bt[3 * CP * KU];            // [l][cp][u] bf16, * 1/sqrt(128)
__device__ ushort g_W2bt[3 * CP * KU];
__device__ ushort g_Woutbt[3 * KU * CP];          // [l][u][cp] bf16, * 1/sqrt(512)
__device__ ushort g_c1b[(size_t)B_N * NKM * CP];  // [b][km][cp] bf16
__device__ ushort g_c2b[(size_t)B_N * NKM * CP];
__device__ ushort g_cb[(size_t)B_N * NKM * CP];   // c_out, [b][km][cp] bf16

__device__ __forceinline__ ushort f2b(float f) {
    uint u = __float_as_uint(f);
    uint r = (u + 0x7fffu + ((u >> 16) & 1u)) >> 16;   // RNE
    return (ushort)r;
}
__device__ __forceinline__ float b2f(ushort h) {
    return __uint_as_float(((uint)h) << 16);
}
__device__ __forceinline__ int l_of_km(int km) { return (km >= 4) ? 2 : (km >= 1 ? 1 : 0); }

// ---------------------------------------------------------------------------
// Gaunt tensor for real orthonormal SH, l<=2: 83 nonzeros, 7 distinct values,
// closed form, baked into a constexpr table so the contraction folds to FMAs.
// ---------------------------------------------------------------------------
__host__ __device__ constexpr int lof(int n) { return n >= 4 ? 2 : (n >= 1 ? 1 : 0); }
__host__ __device__ constexpr int mof(int n) { int l = lof(n); return n - l * l - l; }
__host__ __device__ constexpr bool gaunt_nz(int a, int b, int c) {
    int la = lof(a), lb = lof(b), lc = lof(c);
    if ((la + lb + lc) & 1) return false;
    if (lc > la + lb || la > lb + lc || lb > lc + la) return false;
    int ma = mof(a), mb = mof(b), mc = mof(c);
    int neg = (ma < 0) + (mb < 0) + (mc < 0);
    if (neg & 1) return false;
    int A = ma < 0 ? -ma : ma, Bm = mb < 0 ? -mb : mb, Cm = mc < 0 ? -mc : mc;
    return (A + Bm == Cm) || (Bm + Cm == A) || (Cm + A == Bm);
}
__host__ __device__ constexpr float gaunt_val(int a, int b, int c) {
    int x = a, y = b, z = c, t = 0;
    if (x > y) { t = x; x = y; y = t; }
    if (y > z) { t = y; y = z; z = t; }
    if (x > y) { t = x; x = y; y = t; }
    const float C00 = 0.28209479177387814f;   // 1/(2*sqrt(pi))
    const float A_  = 0.12615662610100802f;
    const float B_  = 0.25231325220201604f;
    const float C_  = 0.21850968611841584f;
    const float D_  = 0.18022375157286857f;
    const float E_  = 0.09011187578643429f;
    const float F_  = 0.15607834722743988f;
    if (x == 0) return C00;
    if (y <= 3) {
        if (z == 6) return (y == 2) ? B_ : -A_;
        if (z == 8) return (x == 1) ? -C_ : C_;
        return C_;
    }
    if (x == 4) return (y == 4) ? -D_ : F_;
    if (x == 5) return (z == 6) ? E_ : -F_;
    if (x == 6) return (y == 6) ? D_ : ((y == 7) ? E_ : -D_);
    return F_;
}
struct GE { int k, i, j; float v; };
struct GTab { GE e[96]; int n; };
__host__ __device__ constexpr GTab make_gt() {
    GTab t{};
    for (int k = 0; k < 9; ++k)
        for (int i = 0; i < 9; ++i)
            for (int j = 0; j < 9; ++j)
                if (gaunt_nz(k, i, j)) { t.e[t.n].k = k; t.e[t.n].i = i; t.e[t.n].j = j;
                                         t.e[t.n].v = gaunt_val(k, i, j); ++t.n; }
    return t;
}
constexpr GTab GT = make_gt();

// ---------------------------------------------------------------------------
// prep_small: W1/W2 -> [l][cp][u]*inv_sqrt(128); Wout -> [l][u][cp]*inv_sqrt(512)
// ---------------------------------------------------------------------------
__global__ void prep_small_kernel(const float* __restrict__ W1, const float* __restrict__ W2,
                                  const float* __restrict__ Wout) {
    int idx = blockIdx.x * 256 + threadIdx.x;    // < 3*512*128 = 196608
    int l = idx >> 16;
    int r = idx & 65535;
    {   // W1bt/W2bt [l][cp][u] <- W[l][u][cp]
        int cp = r >> 7, u = r & 127;
        size_t src = (size_t)l * 65536 + (size_t)u * 512 + cp;
        g_W1bt[idx] = f2b(W1[src] * INV_SQRT_MUL);
        g_W2bt[idx] = f2b(W2[src] * INV_SQRT_MUL);
    }
    {   // Woutbt [l][u][cp] <- Wout[l][cp][u]
        int u = r >> 9, cp = r & 511;
        g_Woutbt[idx] = f2b(Wout[(size_t)l * 65536 + (size_t)cp * 128 + u] * INV_SQRT_4C);
    }
}

// ---------------------------------------------------------------------------
// prep_x: x [B,2048] fp32 -> xb [km][B][u] bf16 via LDS transpose
// ---------------------------------------------------------------------------
__global__ __launch_bounds__(256) void prep_x_kernel(const float* __restrict__ x1,
                                                     const float* __restrict__ x2) {
    __shared__ float L1[2048], L2[2048];
    int b = blockIdx.x, tid = threadIdx.x;
    const float4* r1 = (const float4*)(x1 + (size_t)b * 2048);
    const float4* r2 = (const float4*)(x2 + (size_t)b * 2048);
    #pragma unroll
    for (int i = 0; i < 2; ++i) {
        int q = i * 256 + tid;
        *(float4*)&L1[q * 4] = r1[q];
        *(float4*)&L2[q * 4] = r2[q];
    }
    __syncthreads();
    #pragma unroll
    for (int i = 0; i < 9; ++i) {
        int e = i * 256 + tid;                    // < 2304 = 2 fields * 9 km * 128 u
        int field = e >= 1152;
        int r = e - field * 1152;
        int km = r >> 7, u = r & 127;
        int l = l_of_km(km);
        int col = l * l * 128 + u * (2 * l + 1) + (km - l * l);
        float v = field ? L2[col] : L1[col];
        ushort* dst = field ? g_xb2 : g_xb1;
        dst[(size_t)km * (B_N * KU) + (size_t)b * KU + u] = f2b(v);
    }
}

// ---------------------------------------------------------------------------
// zero_tail: out columns [1152, 2048) = l=3 zero block
// ---------------------------------------------------------------------------
__global__ void zero_tail_kernel(float* __restrict__ out) {
    int idx = blockIdx.x * 256 + threadIdx.x;   // < 2048*224
    int b = idx / 224, q = idx - b * 224;
    *(float4*)&out[(size_t)b * 2048 + 1152 + q * 4] = make_float4(0.f, 0.f, 0.f, 0.f);
}

// ---------------------------------------------------------------------------
// gemm_c: c[b][km][cp] = sum_u xb[km][b][u] * Wbt[l][cp][u]   (bf16 out)
// grid (32, 8, 18 = field*9+km), 64x64 tile, K=128 resident, XOR-swizzled LDS
// ---------------------------------------------------------------------------
__global__ __launch_bounds__(256) void gemm_c_kernel() {
    __shared__ ushort As[64 * 128];
    __shared__ ushort Bs[64 * 128];
    int tid = threadIdx.x;
    int z = blockIdx.z;
    int field = (z >= NKM);
    int km = field ? z - NKM : z;
    int l = l_of_km(km);
    int b0 = blockIdx.x * 64, n0 = blockIdx.y * 64;
    const ushort* xa = (field ? g_xb2 : g_xb1) + (size_t)km * (B_N * KU);
    const ushort* wb = (field ? g_W2bt : g_W1bt) + (size_t)l * 65536;
    ushort* cdst = field ? g_c2b : g_c1b;

    #pragma unroll
    for (int it = 0; it < 4; ++it) {
        int i = it * 256 + tid;            // 16B chunk id, 0..1023
        int row = i >> 4, kg = i & 15;
        int dst = row * 128 + ((kg ^ (row & 7)) << 3);
        *(short8*)&As[dst] = *(const short8*)&xa[(size_t)(b0 + row) * KU + (kg << 3)];
        *(short8*)&Bs[dst] = *(const short8*)&wb[(size_t)(n0 + row) * KU + (kg << 3)];
    }
    __syncthreads();

    int lane = tid & 63, wid = tid >> 6, wr = wid >> 1, wc = wid & 1;
    f32x4 acc[2][2];
    #pragma unroll
    for (int i = 0; i < 2; ++i)
        #pragma unroll
        for (int j = 0; j < 2; ++j) acc[i][j] = (f32x4){0.f, 0.f, 0.f, 0.f};

    #pragma unroll
    for (int ks = 0; ks < 4; ++ks) {
        int kg = ks * 4 + (lane >> 4);
        short8 a[2], b[2];
        #pragma unroll
        for (int i = 0; i < 2; ++i) {
            int row = wr * 32 + i * 16 + (lane & 15);
            a[i] = *(const short8*)&As[row * 128 + ((kg ^ (row & 7)) << 3)];
        }
        #pragma unroll
        for (int j = 0; j < 2; ++j) {
            int row = wc * 32 + j * 16 + (lane & 15);
            b[j] = *(const short8*)&Bs[row * 128 + ((kg ^ (row & 7)) << 3)];
        }
        #pragma unroll
        for (int i = 0; i < 2; ++i)
            #pragma unroll
            for (int j = 0; j < 2; ++j)
                acc[i][j] = __builtin_amdgcn_mfma_f32_16x16x32_bf16(a[i], b[j], acc[i][j], 0, 0, 0);
    }

    #pragma unroll
    for (int i = 0; i < 2; ++i)
        #pragma unroll
        for (int j = 0; j < 2; ++j)
            #pragma unroll
            for (int r = 0; r < 4; ++r) {
                int row = b0 + wr * 32 + i * 16 + ((lane >> 4) << 2) + r;
                int col = n0 + wc * 32 + j * 16 + (lane & 15);
                cdst[((size_t)row * NKM + km) * CP + col] = f2b(acc[i][j][r]);
            }
}

// ---------------------------------------------------------------------------
// middle v4: thread = (b,c). 18 x ushort4 loads + 9 x ushort4 stores (8 B each,
// lane-consecutive -> coalesced 512 B/wave). Gaunt contraction from constexpr
// table folds to a pure FMA chain. launch_bounds(256,2) -> no spill (~150 VGPR).
// ---------------------------------------------------------------------------
__global__ __launch_bounds__(256, 2) void middle_kernel() {
    int idx = blockIdx.x * 256 + threadIdx.x;   // < 2048*128
    int b = idx >> 7, c = idx & 127;
    const ushort* s1 = g_c1b + (size_t)b * (NKM * CP) + c * 4;
    const ushort* s2 = g_c2b + (size_t)b * (NKM * CP) + c * 4;

    float c1[4][9], c2[4][9];
    #pragma unroll
    for (int k = 0; k < 9; ++k) {
        ushort4 v1 = *(const ushort4*)&s1[k * CP];
        ushort4 v2 = *(const ushort4*)&s2[k * CP];
        c1[0][k] = b2f(v1.x); c1[1][k] = b2f(v1.y); c1[2][k] = b2f(v1.z); c1[3][k] = b2f(v1.w);
        c2[0][k] = b2f(v2.x); c2[1][k] = b2f(v2.y); c2[2][k] = b2f(v2.z); c2[3][k] = b2f(v2.w);
    }

    float o[4][9];
    #pragma unroll
    for (int p = 0; p < 4; ++p)
        #pragma unroll
        for (int k = 0; k < 9; ++k) o[p][k] = 0.f;

    #pragma unroll
    for (int e = 0; e < 83; ++e) {
        const int   kk = GT.e[e].k, i = GT.e[e].i, j = GT.e[e].j;
        const float g  = GT.e[e].v;
        o[0][kk] = fmaf(g, c1[0][i] * c2[0][j], o[0][kk]);
        float x1 = fmaf(c1[2][i], c2[3][j], -(c1[3][i] * c2[2][j]));
        float x2 = fmaf(c1[3][i], c2[1][j], -(c1[1][i] * c2[3][j]));
        float x3 = fmaf(c1[1][i], c2[2][j], -(c1[2][i] * c2[1][j]));
        o[1][kk] = fmaf(g, x1, o[1][kk]);
        o[2][kk] = fmaf(g, x2, o[2][kk]);
        o[3][kk] = fmaf(g, x3, o[3][kk]);
    }

    ushort* w = g_cb + (size_t)b * (NKM * CP) + c * 4;
    #pragma unroll
    for (int k = 0; k < 9; ++k) {
        ushort4 v;
        v.x = f2b(o[0][k]); v.y = f2b(o[1][k]); v.z = f2b(o[2][k]); v.w = f2b(o[3][k]);
        *(ushort4*)&w[k * CP] = v;
    }
}

// ---------------------------------------------------------------------------
// out_gemm: out[b][OFF_l + u*d + mi] = sum_cp c_out[b][km][cp] * Woutbt[l][u][cp]
// grid (32, 2, 9 km), 64x64 tile, K=512 in 4 chunks
// ---------------------------------------------------------------------------
__global__ __launch_bounds__(256) void out_gemm_kernel(float* __restrict__ out) {
    __shared__ ushort As[64 * 128];
    __shared__ ushort Bs[64 * 128];
    int tid = threadIdx.x;
    int km = blockIdx.z;
    int l = l_of_km(km);
    int mi = km - l * l, d = 2 * l + 1, OFF = 128 * l * l;
    int b0 = blockIdx.x * 64, u0 = blockIdx.y * 64;

    int lane = tid & 63, wid = tid >> 6, wr = wid >> 1, wc = wid & 1;
    f32x4 acc[2][2];
    #pragma unroll
    for (int i = 0; i < 2; ++i)
        #pragma unroll
        for (int j = 0; j < 2; ++j) acc[i][j] = (f32x4){0.f, 0.f, 0.f, 0.f};

    for (int kc = 0; kc < 4; ++kc) {
        #pragma unroll
        for (int it = 0; it < 4; ++it) {
            int i = it * 256 + tid;
            int row = i >> 4, kg = i & 15;
            int dst = row * 128 + ((kg ^ (row & 7)) << 3);
            *(short8*)&As[dst] = *(const short8*)&g_cb[(size_t)(b0 + row) * (NKM * CP)
                                                       + (size_t)km * CP + kc * 128 + (kg << 3)];
            *(short8*)&Bs[dst] = *(const short8*)&g_Woutbt[(size_t)l * 65536
                                                       + (size_t)(u0 + row) * CP + kc * 128 + (kg << 3)];
        }
        __syncthreads();
        #pragma unroll
        for (int ks = 0; ks < 4; ++ks) {
            int kg = ks * 4 + (lane >> 4);
            short8 a[2], b[2];
            #pragma unroll
            for (int i = 0; i < 2; ++i) {
                int row = wr * 32 + i * 16 + (lane & 15);
                a[i] = *(const short8*)&As[row * 128 + ((kg ^ (row & 7)) << 3)];
            }
            #pragma unroll
            for (int j = 0; j < 2; ++j) {
                int row = wc * 32 + j * 16 + (lane & 15);
                b[j] = *(const short8*)&Bs[row * 128 + ((kg ^ (row & 7)) << 3)];
            }
            #pragma unroll
            for (int i = 0; i < 2; ++i)
                #pragma unroll
                for (int j = 0; j < 2; ++j)
                    acc[i][j] = __builtin_amdgcn_mfma_f32_16x16x32_bf16(a[i], b[j], acc[i][j], 0, 0, 0);
        }
        __syncthreads();
    }

    #pragma unroll
    for (int i = 0; i < 2; ++i)
        #pragma unroll
        for (int j = 0; j < 2; ++j)
            #pragma unroll
            for (int r = 0; r < 4; ++r) {
                int row = b0 + wr * 32 + i * 16 + ((lane >> 4) << 2) + r;
                int u   = u0 + wc * 32 + j * 16 + (lane & 15);
                out[(size_t)row * 2048 + OFF + u * d + mi] = acc[i][j][r];
            }
}

// ---------------------------------------------------------------------------
extern "C" void kernel_launch(void* const* d_in, const int* in_sizes, int n_in,
                              void* d_out, int out_size, void* d_ws, size_t ws_size,
                              hipStream_t stream) {
    const float* x1   = (const float*)d_in[0];
    const float* x2   = (const float*)d_in[1];
    const float* W1   = (const float*)d_in[2];
    const float* W2   = (const float*)d_in[3];
    const float* Wout = (const float*)d_in[4];
    float* out = (float*)d_out;

    zero_tail_kernel<<<1792, 256, 0, stream>>>(out);
    prep_small_kernel<<<768, 256, 0, stream>>>(W1, W2, Wout);
    prep_x_kernel<<<B_N, 256, 0, stream>>>(x1, x2);

    gemm_c_kernel<<<dim3(B_N / 64, CP / 64, 18), 256, 0, stream>>>();
    middle_kernel<<<(B_N * 128) / 256, 256, 0, stream>>>();
    out_gemm_kernel<<<dim3(B_N / 64, 128 / 64, NKM), 256, 0, stream>>>(out);
}